// Round 1
// baseline (978.518 us; speedup 1.0000x reference)
//
#include <hip/hip_runtime.h>
#include <hip/hip_bf16.h>

#define H 128           // H_IN == H_OUT == 128
#define TILE_M 64
#define BK 32

// ---------------------------------------------------------------------------
// degree count: deg[dst] += 1 per edge
__global__ __launch_bounds__(256) void deg_kernel(const int* __restrict__ ei,
                                                  float* __restrict__ deg, int E) {
    int e = blockIdx.x * 256 + threadIdx.x;
    if (e < E) atomicAdd(&deg[ei[E + e]], 1.0f);
}

// deg -> dinv = rsqrt(deg + 2) in place
__global__ __launch_bounds__(256) void dinv_kernel(float* __restrict__ deg, int N) {
    int i = blockIdx.x * 256 + threadIdx.x;
    if (i < N) deg[i] = rsqrtf(deg[i] + 2.0f);
}

// ---------------------------------------------------------------------------
// Y[M,128] = X[M,128] @ W[128,128]  (fp32, register-blocked 8x4 per thread)
// block: 256 threads, tile 64 rows x 128 cols
__global__ __launch_bounds__(256) void gemm_kernel(const float* __restrict__ X,
                                                   const float* __restrict__ W,
                                                   float* __restrict__ Y, int N) {
    __shared__ float xs[BK][TILE_M + 4];   // transposed: xs[k][m], stride 68 (16B-aligned)
    __shared__ float wt[BK][H + 4];        // wt[k][c], stride 132 (16B-aligned)

    const int tid = threadIdx.x;
    const int tx = tid & 31;               // col group: cols tx*4 .. tx*4+3
    const int ty = tid >> 5;               // row group: rows ty*8 .. ty*8+7
    const int row0 = blockIdx.x * TILE_M;

    float acc[8][4] = {};

    for (int k0 = 0; k0 < H; k0 += BK) {
        // X tile: 64 rows x 32 k -> 512 float4, 2 per thread, store transposed
        #pragma unroll
        for (int l = 0; l < 2; ++l) {
            int idx = tid + l * 256;       // 0..511
            int m = idx >> 3;              // 0..63
            int kq = idx & 7;              // float4 index within 32-k slice
            int grow = row0 + m;
            float4 v = make_float4(0.f, 0.f, 0.f, 0.f);
            if (grow < N) v = *(const float4*)&X[grow * H + k0 + kq * 4];
            xs[kq * 4 + 0][m] = v.x;
            xs[kq * 4 + 1][m] = v.y;
            xs[kq * 4 + 2][m] = v.z;
            xs[kq * 4 + 3][m] = v.w;
        }
        // W tile: 32 k x 128 cols -> 1024 float4, 4 per thread
        #pragma unroll
        for (int l = 0; l < 4; ++l) {
            int idx = tid + l * 256;       // 0..1023
            int kr = idx >> 5;             // 0..31
            int cq = idx & 31;             // float4 index within row
            *(float4*)&wt[kr][cq * 4] = *(const float4*)&W[(k0 + kr) * H + cq * 4];
        }
        __syncthreads();

        #pragma unroll
        for (int kk = 0; kk < BK; ++kk) {
            float4 a0 = *(const float4*)&xs[kk][ty * 8];
            float4 a1 = *(const float4*)&xs[kk][ty * 8 + 4];
            float4 b  = *(const float4*)&wt[kk][tx * 4];
            float a[8] = {a0.x, a0.y, a0.z, a0.w, a1.x, a1.y, a1.z, a1.w};
            float bb[4] = {b.x, b.y, b.z, b.w};
            #pragma unroll
            for (int i = 0; i < 8; ++i)
                #pragma unroll
                for (int j = 0; j < 4; ++j)
                    acc[i][j] += a[i] * bb[j];
        }
        __syncthreads();
    }

    #pragma unroll
    for (int i = 0; i < 8; ++i) {
        int grow = row0 + ty * 8 + i;
        if (grow < N) {
            float4 v = make_float4(acc[i][0], acc[i][1], acc[i][2], acc[i][3]);
            *(float4*)&Y[grow * H + tx * 4] = v;
        }
    }
}

// ---------------------------------------------------------------------------
// per edge: out[dst][:] += dinv[src]*dinv[dst] * h[src][:]
// 256 threads = 2 edges per block, thread j of 128 handles one feature
__global__ __launch_bounds__(256) void scatter_kernel(const int* __restrict__ ei,
                                                      const float* __restrict__ h,
                                                      const float* __restrict__ dinv,
                                                      float* __restrict__ out, int E) {
    int e = blockIdx.x * 2 + (threadIdx.x >> 7);
    if (e >= E) return;
    int j = threadIdx.x & 127;
    int s = ei[e];
    int d = ei[E + e];
    float norm = dinv[s] * dinv[d];
    atomicAdd(&out[d * H + j], norm * h[s * H + j]);
}

// ---------------------------------------------------------------------------
// out = ELU( out + 2*dinv^2 * h + b_conv + b_skip )
__global__ __launch_bounds__(256) void final_kernel(float* __restrict__ out,
                                                    const float* __restrict__ h,
                                                    const float* __restrict__ dinv,
                                                    const float* __restrict__ b_conv,
                                                    const float* __restrict__ b_skip,
                                                    int N) {
    int idx = blockIdx.x * 256 + threadIdx.x;
    if (idx >= N * H) return;
    int i = idx >> 7;
    int j = idx & 127;
    float di = dinv[i];
    float v = out[idx] + 2.0f * di * di * h[idx] + b_conv[j] + b_skip[j];
    out[idx] = v > 0.0f ? v : 0.1f * (__expf(v) - 1.0f);
}

// ---------------------------------------------------------------------------
extern "C" void kernel_launch(void* const* d_in, const int* in_sizes, int n_in,
                              void* d_out, int out_size, void* d_ws, size_t ws_size,
                              hipStream_t stream) {
    const float* x   = (const float*)d_in[0];
    const int*   ei  = (const int*)d_in[1];
    const float* Wc  = (const float*)d_in[2];
    const float* bc  = (const float*)d_in[3];
    const float* Wsk = (const float*)d_in[4];
    const float* bsk = (const float*)d_in[5];
    float* out = (float*)d_out;

    const int N = in_sizes[0] / H;     // 100000
    const int E = in_sizes[1] / 2;     // 1600000

    // workspace: [0, 1MB) deg/dinv ; [1MB, 1MB+N*H*4) h
    float* deg = (float*)d_ws;
    float* h   = (float*)((char*)d_ws + (1u << 20));

    hipMemsetAsync(deg, 0, (size_t)N * sizeof(float), stream);

    deg_kernel<<<(E + 255) / 256, 256, 0, stream>>>(ei, deg, E);
    dinv_kernel<<<(N + 255) / 256, 256, 0, stream>>>(deg, N);

    // h = x @ W_conv   (into workspace)
    gemm_kernel<<<(N + TILE_M - 1) / TILE_M, 256, 0, stream>>>(x, Wc, h, N);
    // out = x @ W_skip (pure overwrite of poisoned d_out)
    gemm_kernel<<<(N + TILE_M - 1) / TILE_M, 256, 0, stream>>>(x, Wsk, out, N);

    // out += scatter of normalized messages
    scatter_kernel<<<(E + 1) / 2, 256, 0, stream>>>(ei, h, deg, out, E);

    // out = ELU(out + selfloop*h + biases)
    final_kernel<<<(N * H + 255) / 256, 256, 0, stream>>>(out, h, deg, bc, bsk, N);
}

// Round 2
// 519.616 us; speedup vs baseline: 1.8832x; 1.8832x over previous
//
#include <hip/hip_runtime.h>
#include <hip/hip_bf16.h>

#define H 128           // H_IN == H_OUT == 128
#define TILE_M 64
#define BK 32

// ---------------------------------------------------------------------------
// degree histogram (int): deg[dst] += 1 per edge
__global__ __launch_bounds__(256) void deg_kernel(const int* __restrict__ ei,
                                                  int* __restrict__ deg, int E) {
    int e = blockIdx.x * 256 + threadIdx.x;
    if (e < E) atomicAdd(&deg[ei[E + e]], 1);
}

// dinv = rsqrt(deg + 2)
__global__ __launch_bounds__(256) void dinv_kernel(const int* __restrict__ deg,
                                                   float* __restrict__ dinv, int N) {
    int i = blockIdx.x * 256 + threadIdx.x;
    if (i < N) dinv[i] = rsqrtf((float)deg[i] + 2.0f);
}

// ---------------------------------------------------------------------------
// 3-phase exclusive scan of deg -> cursor (CSR row starts)
__global__ __launch_bounds__(256) void block_reduce_kernel(const int* __restrict__ deg,
                                                           int* __restrict__ bsums, int N) {
    __shared__ int s[256];
    int i = blockIdx.x * 256 + threadIdx.x;
    s[threadIdx.x] = (i < N) ? deg[i] : 0;
    __syncthreads();
    for (int off = 128; off > 0; off >>= 1) {
        if (threadIdx.x < off) s[threadIdx.x] += s[threadIdx.x + off];
        __syncthreads();
    }
    if (threadIdx.x == 0) bsums[blockIdx.x] = s[0];
}

__global__ __launch_bounds__(512) void scan_sums_kernel(int* __restrict__ bsums, int nb) {
    __shared__ int s[512];
    int t = threadIdx.x;
    int v = (t < nb) ? bsums[t] : 0;
    s[t] = v;
    __syncthreads();
    for (int off = 1; off < 512; off <<= 1) {
        int add = (t >= off) ? s[t - off] : 0;
        __syncthreads();
        s[t] += add;
        __syncthreads();
    }
    if (t < nb) bsums[t] = s[t] - v;   // exclusive
}

__global__ __launch_bounds__(256) void block_scan_kernel(const int* __restrict__ deg,
                                                         const int* __restrict__ bsums,
                                                         int* __restrict__ cursor, int N) {
    __shared__ int s[256];
    int i = blockIdx.x * 256 + threadIdx.x;
    int t = threadIdx.x;
    int v = (i < N) ? deg[i] : 0;
    s[t] = v;
    __syncthreads();
    for (int off = 1; off < 256; off <<= 1) {
        int add = (t >= off) ? s[t - off] : 0;
        __syncthreads();
        s[t] += add;
        __syncthreads();
    }
    if (i < N) cursor[i] = bsums[blockIdx.x] + s[t] - v;  // exclusive scan
}

// bucket edges by dst: entries[slot] = src.  After this, cursor[i] == row end.
__global__ __launch_bounds__(256) void bucket_kernel(const int* __restrict__ ei,
                                                     int* __restrict__ cursor,
                                                     int* __restrict__ entries, int E) {
    int e = blockIdx.x * 256 + threadIdx.x;
    if (e >= E) return;
    int s = ei[e], d = ei[E + e];
    int slot = atomicAdd(&cursor[d], 1);
    entries[slot] = s;
}

// ---------------------------------------------------------------------------
// Dual GEMM: Hc = X @ Wc, Hs = X @ Ws (read X once). 64-row tiles, 8x4x2 regs.
__global__ __launch_bounds__(256) void gemm_dual_kernel(const float* __restrict__ X,
                                                        const float* __restrict__ Wc,
                                                        const float* __restrict__ Ws,
                                                        float* __restrict__ Hc,
                                                        float* __restrict__ Hs, int N) {
    __shared__ float xs[BK][TILE_M + 4];
    __shared__ float wc[BK][H + 4];
    __shared__ float wsm[BK][H + 4];
    const int tid = threadIdx.x;
    const int tx = tid & 31;
    const int ty = tid >> 5;
    const int row0 = blockIdx.x * TILE_M;
    float accc[8][4] = {};
    float accs[8][4] = {};

    for (int k0 = 0; k0 < H; k0 += BK) {
        #pragma unroll
        for (int l = 0; l < 2; ++l) {
            int idx = tid + l * 256;       // 0..511
            int m = idx >> 3;
            int kq = idx & 7;
            int grow = row0 + m;
            float4 v = make_float4(0.f, 0.f, 0.f, 0.f);
            if (grow < N) v = *(const float4*)&X[grow * H + k0 + kq * 4];
            xs[kq * 4 + 0][m] = v.x;
            xs[kq * 4 + 1][m] = v.y;
            xs[kq * 4 + 2][m] = v.z;
            xs[kq * 4 + 3][m] = v.w;
        }
        #pragma unroll
        for (int l = 0; l < 4; ++l) {
            int idx = tid + l * 256;       // 0..1023
            int kr = idx >> 5;
            int cq = idx & 31;
            *(float4*)&wc[kr][cq * 4]  = *(const float4*)&Wc[(k0 + kr) * H + cq * 4];
            *(float4*)&wsm[kr][cq * 4] = *(const float4*)&Ws[(k0 + kr) * H + cq * 4];
        }
        __syncthreads();

        #pragma unroll
        for (int kk = 0; kk < BK; ++kk) {
            float4 a0 = *(const float4*)&xs[kk][ty * 8];
            float4 a1 = *(const float4*)&xs[kk][ty * 8 + 4];
            float a[8] = {a0.x, a0.y, a0.z, a0.w, a1.x, a1.y, a1.z, a1.w};
            float4 b0 = *(const float4*)&wc[kk][tx * 4];
            float4 b1 = *(const float4*)&wsm[kk][tx * 4];
            float bcv[4] = {b0.x, b0.y, b0.z, b0.w};
            float bsv[4] = {b1.x, b1.y, b1.z, b1.w};
            #pragma unroll
            for (int i = 0; i < 8; ++i) {
                #pragma unroll
                for (int j = 0; j < 4; ++j) {
                    accc[i][j] += a[i] * bcv[j];
                    accs[i][j] += a[i] * bsv[j];
                }
            }
        }
        __syncthreads();
    }

    #pragma unroll
    for (int i = 0; i < 8; ++i) {
        int grow = row0 + ty * 8 + i;
        if (grow < N) {
            *(float4*)&Hc[grow * H + tx * 4] =
                make_float4(accc[i][0], accc[i][1], accc[i][2], accc[i][3]);
            *(float4*)&Hs[grow * H + tx * 4] =
                make_float4(accs[i][0], accs[i][1], accs[i][2], accs[i][3]);
        }
    }
}

// ---------------------------------------------------------------------------
// Gather aggregation + fused epilogue. One wave (64 lanes) per node; each lane
// owns 2 features (float2). No atomics; output row written exactly once.
__global__ __launch_bounds__(256) void agg_kernel(const int* __restrict__ entries,
                                                  const int* __restrict__ cursor,
                                                  const int* __restrict__ deg,
                                                  const float* __restrict__ dinv,
                                                  const float* __restrict__ h,
                                                  const float* __restrict__ bc,
                                                  const float* __restrict__ bsk,
                                                  float* __restrict__ out, int N) {
    int node = blockIdx.x * 4 + (threadIdx.x >> 6);
    if (node >= N) return;
    int lane = threadIdx.x & 63;
    int end = cursor[node];            // after bucketing: row end
    int start = end - deg[node];
    float dd = dinv[node];
    const float2* h2 = (const float2*)h;
    float2 acc = make_float2(0.f, 0.f);

    for (int c = start; c < end; c += 64) {
        int rem = end - c;
        int src = 0;
        float nm = 0.f;
        if (lane < rem) {
            src = entries[c + lane];
            nm = dinv[src] * dd;
        }
        int cnt = rem < 64 ? rem : 64;
        for (int t = 0; t < cnt; ++t) {
            int ss = __shfl(src, t);
            float w = __shfl(nm, t);
            float2 hv = h2[ss * 64 + lane];
            acc.x += w * hv.x;
            acc.y += w * hv.y;
        }
    }

    float2 hs = h2[node * 64 + lane];
    float sl = 2.f * dd * dd;
    float2 sk = ((const float2*)out)[node * 64 + lane];   // skip = x @ W_skip
    float2 b1 = ((const float2*)bc)[lane];
    float2 b2 = ((const float2*)bsk)[lane];
    float vx = acc.x + sl * hs.x + sk.x + b1.x + b2.x;
    float vy = acc.y + sl * hs.y + sk.y + b1.y + b2.y;
    vx = vx > 0.f ? vx : 0.1f * (__expf(vx) - 1.f);
    vy = vy > 0.f ? vy : 0.1f * (__expf(vy) - 1.f);
    ((float2*)out)[node * 64 + lane] = make_float2(vx, vy);
}

// ---------------------------------------------------------------------------
extern "C" void kernel_launch(void* const* d_in, const int* in_sizes, int n_in,
                              void* d_out, int out_size, void* d_ws, size_t ws_size,
                              hipStream_t stream) {
    const float* x   = (const float*)d_in[0];
    const int*   ei  = (const int*)d_in[1];
    const float* Wc  = (const float*)d_in[2];
    const float* bc  = (const float*)d_in[3];
    const float* Wsk = (const float*)d_in[4];
    const float* bsk = (const float*)d_in[5];
    float* out = (float*)d_out;

    const int N = in_sizes[0] / H;     // 100000
    const int E = in_sizes[1] / 2;     // 1600000
    const int nb = (N + 255) / 256;    // 391 scan blocks (<=512)

    // workspace layout (bytes):
    //   [0, 512K)        deg (int, N)
    //   [512K, 1M)       dinv (float, N)
    //   [1M, 1.5M)       cursor (int, N)
    //   [1.5M, 1.5M+8K)  bsums (int, nb)
    //   [1600K, +6.4M)   entries (int, E)
    //   [8M, +51.2M)     h (float, N*H)
    char* w = (char*)d_ws;
    int*   deg     = (int*)w;
    float* dinv    = (float*)(w + 512u * 1024);
    int*   cursor  = (int*)(w + 1024u * 1024);
    int*   bsums   = (int*)(w + 1536u * 1024);
    int*   entries = (int*)(w + 1600u * 1024);
    float* h       = (float*)(w + 8u * 1024 * 1024);

    hipMemsetAsync(deg, 0, (size_t)N * sizeof(int), stream);

    deg_kernel<<<(E + 255) / 256, 256, 0, stream>>>(ei, deg, E);
    dinv_kernel<<<(N + 255) / 256, 256, 0, stream>>>(deg, dinv, N);

    block_reduce_kernel<<<nb, 256, 0, stream>>>(deg, bsums, N);
    scan_sums_kernel<<<1, 512, 0, stream>>>(bsums, nb);
    block_scan_kernel<<<nb, 256, 0, stream>>>(deg, bsums, cursor, N);
    bucket_kernel<<<(E + 255) / 256, 256, 0, stream>>>(ei, cursor, entries, E);

    // h = x @ W_conv (ws), out = x @ W_skip (overwrites poison)
    gemm_dual_kernel<<<(N + TILE_M - 1) / TILE_M, 256, 0, stream>>>(x, Wc, Wsk, h, out, N);

    // out = ELU(gather(norm * h[src]) + selfloop + skip + biases)
    agg_kernel<<<(N + 3) / 4, 256, 0, stream>>>(entries, cursor, deg, dinv, h, bc, bsk, out, N);
}

// Round 3
// 465.280 us; speedup vs baseline: 2.1031x; 1.1168x over previous
//
#include <hip/hip_runtime.h>
#include <hip/hip_bf16.h>

#define H 128           // H_IN == H_OUT == 128

typedef __attribute__((ext_vector_type(8))) short short8;
typedef __attribute__((ext_vector_type(4))) float f32x4;

__device__ inline unsigned short f2bf(float f) {
    union { float f; unsigned int u; } v; v.f = f;
    unsigned int r = (v.u + 0x7fffu + ((v.u >> 16) & 1u)) >> 16;
    return (unsigned short)r;
}
__device__ inline float bf2f(unsigned short h) {
    union { unsigned int u; float f; } v; v.u = ((unsigned int)h) << 16;
    return v.f;
}

// ---------------------------------------------------------------------------
// degree histogram (int): deg[dst] += 1 per edge
__global__ __launch_bounds__(256) void deg_kernel(const int* __restrict__ ei,
                                                  int* __restrict__ deg, int E) {
    int e = blockIdx.x * 256 + threadIdx.x;
    if (e < E) atomicAdd(&deg[ei[E + e]], 1);
}

// dinv = rsqrt(deg + 2)
__global__ __launch_bounds__(256) void dinv_kernel(const int* __restrict__ deg,
                                                   float* __restrict__ dinv, int N) {
    int i = blockIdx.x * 256 + threadIdx.x;
    if (i < N) dinv[i] = rsqrtf((float)deg[i] + 2.0f);
}

// cast x (fp32) -> xh (bf16), 8 elems/thread
__global__ __launch_bounds__(256) void cast_kernel(const float* __restrict__ x,
                                                   unsigned short* __restrict__ xh,
                                                   int total8) {
    int i = blockIdx.x * 256 + threadIdx.x;
    if (i >= total8) return;
    const float4* xp = (const float4*)x;
    float4 a = xp[2 * i], b = xp[2 * i + 1];
    short8 v;
    v[0] = (short)f2bf(a.x); v[1] = (short)f2bf(a.y);
    v[2] = (short)f2bf(a.z); v[3] = (short)f2bf(a.w);
    v[4] = (short)f2bf(b.x); v[5] = (short)f2bf(b.y);
    v[6] = (short)f2bf(b.z); v[7] = (short)f2bf(b.w);
    ((short8*)xh)[i] = v;
}

// ---------------------------------------------------------------------------
// 3-phase exclusive scan of deg -> cursor (CSR row starts)
__global__ __launch_bounds__(256) void block_reduce_kernel(const int* __restrict__ deg,
                                                           int* __restrict__ bsums, int N) {
    __shared__ int s[256];
    int i = blockIdx.x * 256 + threadIdx.x;
    s[threadIdx.x] = (i < N) ? deg[i] : 0;
    __syncthreads();
    for (int off = 128; off > 0; off >>= 1) {
        if (threadIdx.x < off) s[threadIdx.x] += s[threadIdx.x + off];
        __syncthreads();
    }
    if (threadIdx.x == 0) bsums[blockIdx.x] = s[0];
}

__global__ __launch_bounds__(512) void scan_sums_kernel(int* __restrict__ bsums, int nb) {
    __shared__ int s[512];
    int t = threadIdx.x;
    int v = (t < nb) ? bsums[t] : 0;
    s[t] = v;
    __syncthreads();
    for (int off = 1; off < 512; off <<= 1) {
        int add = (t >= off) ? s[t - off] : 0;
        __syncthreads();
        s[t] += add;
        __syncthreads();
    }
    if (t < nb) bsums[t] = s[t] - v;   // exclusive
}

__global__ __launch_bounds__(256) void block_scan_kernel(const int* __restrict__ deg,
                                                         const int* __restrict__ bsums,
                                                         int* __restrict__ cursor, int N) {
    __shared__ int s[256];
    int i = blockIdx.x * 256 + threadIdx.x;
    int t = threadIdx.x;
    int v = (i < N) ? deg[i] : 0;
    s[t] = v;
    __syncthreads();
    for (int off = 1; off < 256; off <<= 1) {
        int add = (t >= off) ? s[t - off] : 0;
        __syncthreads();
        s[t] += add;
        __syncthreads();
    }
    if (i < N) cursor[i] = bsums[blockIdx.x] + s[t] - v;  // exclusive scan
}

// bucket edges by dst: entries[slot] = src.  After this, cursor[i] == row end.
__global__ __launch_bounds__(256) void bucket_kernel(const int* __restrict__ ei,
                                                     int* __restrict__ cursor,
                                                     int* __restrict__ entries, int E) {
    int e = blockIdx.x * 256 + threadIdx.x;
    if (e >= E) return;
    int s = ei[e], d = ei[E + e];
    int slot = atomicAdd(&cursor[d], 1);
    entries[slot] = s;
}

// ---------------------------------------------------------------------------
// Pack W matrices into MFMA B-fragment layout (bf16), 3 planes:
//   mat 0: Wc_hi   mat 1: Ws_hi   mat 2: Ws_lo
// frag index: ((mat*4 + kstep)*8 + ntile)*64 + lane, each short8 (16B):
//   elem j = W[kstep*32 + (lane>>4)*8 + j][ntile*16 + (lane&15)]
__global__ __launch_bounds__(256) void wpack_kernel(const float* __restrict__ Wc,
                                                    const float* __restrict__ Ws,
                                                    short8* __restrict__ wp) {
    int t = blockIdx.x * 256 + threadIdx.x;   // 0..2047
    if (t >= 2048) return;
    int lane = t & 63;
    int nt = (t >> 6) & 7;
    int ks = t >> 9;
    int kbase = ks * 32 + (lane >> 4) * 8;
    int col = nt * 16 + (lane & 15);
    short8 whc, whs, wls;
    #pragma unroll
    for (int j = 0; j < 8; ++j) {
        float wc = Wc[(kbase + j) * H + col];
        float ws = Ws[(kbase + j) * H + col];
        unsigned short hc = f2bf(wc);
        unsigned short hs = f2bf(ws);
        whc[j] = (short)hc;
        whs[j] = (short)hs;
        wls[j] = (short)f2bf(ws - bf2f(hs));
    }
    int base = (ks * 8 + nt) * 64 + lane;
    wp[base] = whc;                    // mat 0
    wp[2048 + base] = whs;             // mat 1
    wp[4096 + base] = wls;             // mat 2
}

// ---------------------------------------------------------------------------
// Gather aggregation on bf16 x: z = sum(norm * x[src]) + 2*d^2*x[node], bf16 out.
// One wave per node, lane owns 2 features.
__global__ __launch_bounds__(256) void agg_kernel(const int* __restrict__ entries,
                                                  const int* __restrict__ cursor,
                                                  const int* __restrict__ deg,
                                                  const float* __restrict__ dinv,
                                                  const unsigned short* __restrict__ xh,
                                                  unsigned short* __restrict__ z, int N) {
    int node = blockIdx.x * 4 + (threadIdx.x >> 6);
    if (node >= N) return;
    int lane = threadIdx.x & 63;
    int end = cursor[node];            // after bucketing: row end
    int start = end - deg[node];
    float dd = dinv[node];
    const uint* x2 = (const uint*)xh;  // bf16 pair per lane
    float accx = 0.f, accy = 0.f;

    for (int c = start; c < end; c += 64) {
        int rem = end - c;
        int src = 0;
        float nm = 0.f;
        if (lane < rem) {
            src = entries[c + lane];
            nm = dinv[src] * dd;
        }
        int cnt = rem < 64 ? rem : 64;
        for (int t = 0; t < cnt; ++t) {
            int ss = __shfl(src, t);
            float w = __shfl(nm, t);
            uint hv = x2[ss * 64 + lane];
            accx += w * bf2f((unsigned short)(hv & 0xffffu));
            accy += w * bf2f((unsigned short)(hv >> 16));
        }
    }

    uint sv = x2[node * 64 + lane];
    float sl = 2.f * dd * dd;
    accx += sl * bf2f((unsigned short)(sv & 0xffffu));
    accy += sl * bf2f((unsigned short)(sv >> 16));
    uint outw = (uint)f2bf(accx) | ((uint)f2bf(accy) << 16);
    ((uint*)z)[node * 64 + lane] = outw;
}

// ---------------------------------------------------------------------------
// MFMA GEMM: out = ELU( z@Wc + x@Ws + bc + bsk ), split-bf16 on the x path.
// Block = 4 waves x 16 rows = 64 rows. 8 n-tiles of 16 cols. K = 128 = 4 steps.
__global__ __launch_bounds__(256) void gemm_kernel(const unsigned short* __restrict__ zb,
                                                   const float* __restrict__ x,
                                                   const short8* __restrict__ wp,
                                                   const float* __restrict__ bc,
                                                   const float* __restrict__ bsk,
                                                   float* __restrict__ out, int N) {
    const int lane = threadIdx.x & 63;
    const int wave = threadIdx.x >> 6;
    const int m = lane & 15;
    const int quad = lane >> 4;
    const int row = blockIdx.x * 64 + wave * 16 + m;     // A-row this lane loads
    const bool rowok = row < N;

    f32x4 acc[8];
    #pragma unroll
    for (int i = 0; i < 8; ++i) acc[i] = (f32x4){0.f, 0.f, 0.f, 0.f};

    #pragma unroll
    for (int ks = 0; ks < 4; ++ks) {
        const int k0 = ks * 32 + quad * 8;
        short8 za = {0, 0, 0, 0, 0, 0, 0, 0};
        short8 xa_h = {0, 0, 0, 0, 0, 0, 0, 0};
        short8 xa_l = {0, 0, 0, 0, 0, 0, 0, 0};
        if (rowok) {
            za = ((const short8*)zb)[(row * H + k0) >> 3];
            float4 a = *(const float4*)&x[row * H + k0];
            float4 b = *(const float4*)&x[row * H + k0 + 4];
            float xv[8] = {a.x, a.y, a.z, a.w, b.x, b.y, b.z, b.w};
            #pragma unroll
            for (int j = 0; j < 8; ++j) {
                unsigned short h = f2bf(xv[j]);
                xa_h[j] = (short)h;
                xa_l[j] = (short)f2bf(xv[j] - bf2f(h));
            }
        }
        #pragma unroll
        for (int nt = 0; nt < 8; ++nt) {
            int base = (ks * 8 + nt) * 64 + lane;
            short8 bch = wp[base];
            short8 bsh = wp[2048 + base];
            short8 bsl = wp[4096 + base];
            acc[nt] = __builtin_amdgcn_mfma_f32_16x16x32_bf16(za, bch, acc[nt], 0, 0, 0);
            acc[nt] = __builtin_amdgcn_mfma_f32_16x16x32_bf16(xa_h, bsh, acc[nt], 0, 0, 0);
            acc[nt] = __builtin_amdgcn_mfma_f32_16x16x32_bf16(xa_l, bsh, acc[nt], 0, 0, 0);
            acc[nt] = __builtin_amdgcn_mfma_f32_16x16x32_bf16(xa_h, bsl, acc[nt], 0, 0, 0);
        }
    }

    // epilogue: D layout col=lane&15 (=m), row=quad*4+reg
    const int orow_base = blockIdx.x * 64 + wave * 16 + quad * 4;
    #pragma unroll
    for (int nt = 0; nt < 8; ++nt) {
        int col = nt * 16 + m;
        float bias = bc[col] + bsk[col];
        #pragma unroll
        for (int r = 0; r < 4; ++r) {
            int orow = orow_base + r;
            if (orow < N) {
                float v = acc[nt][r] + bias;
                v = v > 0.f ? v : 0.1f * (__expf(v) - 1.f);
                out[orow * H + col] = v;
            }
        }
    }
}

// ---------------------------------------------------------------------------
extern "C" void kernel_launch(void* const* d_in, const int* in_sizes, int n_in,
                              void* d_out, int out_size, void* d_ws, size_t ws_size,
                              hipStream_t stream) {
    const float* x   = (const float*)d_in[0];
    const int*   ei  = (const int*)d_in[1];
    const float* Wc  = (const float*)d_in[2];
    const float* bc  = (const float*)d_in[3];
    const float* Wsk = (const float*)d_in[4];
    const float* bsk = (const float*)d_in[5];
    float* out = (float*)d_out;

    const int N = in_sizes[0] / H;     // 100000
    const int E = in_sizes[1] / 2;     // 1600000
    const int nb = (N + 255) / 256;    // 391 scan blocks (<=512)

    // workspace layout (bytes):
    //   [0, 0.5M)      deg (int, N)
    //   [0.5M, 1M)     dinv (float, N)
    //   [1M, 1.5M)     cursor (int, N)
    //   [1.5M, +8K)    bsums
    //   [1.6M, +96K)   packed W (3 x 2048 short8)
    //   [2M, 8.4M)     entries (int, E)
    //   [8.5M, 34.1M)  xh (bf16, N*H)
    //   [34.5M, 60.1M) z (bf16, N*H)
    char* w = (char*)d_ws;
    int*            deg     = (int*)w;
    float*          dinv    = (float*)(w + 512u * 1024);
    int*            cursor  = (int*)(w + 1024u * 1024);
    int*            bsums   = (int*)(w + 1536u * 1024);
    short8*         wp      = (short8*)(w + 1664u * 1024);
    int*            entries = (int*)(w + 2048u * 1024);
    unsigned short* xh      = (unsigned short*)(w + 8704u * 1024);
    unsigned short* z       = (unsigned short*)(w + 35328u * 1024);

    hipMemsetAsync(deg, 0, (size_t)N * sizeof(int), stream);

    deg_kernel<<<(E + 255) / 256, 256, 0, stream>>>(ei, deg, E);
    dinv_kernel<<<(N + 255) / 256, 256, 0, stream>>>(deg, dinv, N);
    cast_kernel<<<(N * H / 8 + 255) / 256, 256, 0, stream>>>(x, xh, N * H / 8);

    block_reduce_kernel<<<nb, 256, 0, stream>>>(deg, bsums, N);
    scan_sums_kernel<<<1, 512, 0, stream>>>(bsums, nb);
    block_scan_kernel<<<nb, 256, 0, stream>>>(deg, bsums, cursor, N);
    bucket_kernel<<<(E + 255) / 256, 256, 0, stream>>>(ei, cursor, entries, E);

    wpack_kernel<<<8, 256, 0, stream>>>(Wc, Wsk, wp);

    // z = sum(norm * x[src]) + selfloop (bf16)
    agg_kernel<<<(N + 3) / 4, 256, 0, stream>>>(entries, cursor, deg, dinv, xh, z, N);

    // out = ELU(z@Wc + x@Ws + biases)
    gemm_kernel<<<(N + 63) / 64, 256, 0, stream>>>(z, x, wp, bc, bsk, out, N);
}